// Round 5
// baseline (254.829 us; speedup 1.0000x reference)
//
#include <hip/hip_runtime.h>

typedef short bf8_t __attribute__((ext_vector_type(8)));   // 8 x bf16
typedef float f32x4 __attribute__((ext_vector_type(4)));

static constexpr int Bc      = 2;
static constexpr int Nv      = 163842;
static constexpr int CIN     = 64;
static constexpr int COUT    = 64;
static constexpr int KK      = 448;                 // 7*CIN
static constexpr int SEVEN_N = 7 * Nv;              // 1146894
static constexpr int Q       = 3;                   // rows per channel per tile
static constexpr int LM      = Q * KK;              // 1344
static constexpr int MSTAGE  = LM + KK;             // 1792 staged m-values (halo)
static constexpr int STRIDE  = 1800;                // 900 dw; 900%32=4 -> 2-way (free)
static constexpr int NT      = (SEVEN_N + LM - 1) / LM;      // 854 m-tiles
static constexpr int THREADS = 512;                 // 8 waves
static constexpr int PAIRS   = MSTAGE / 2;          // 896
static constexpr int PPP     = THREADS / 4;         // 128 pairs per pass
static constexpr int PASSES  = PAIRS / PPP;         // 7 (exact)

__device__ inline unsigned pack2_bf16(float a, float b) {
    unsigned ua = __builtin_bit_cast(unsigned, a);
    unsigned ub = __builtin_bit_cast(unsigned, b);
    ua = (ua + 0x7FFFu + ((ua >> 16) & 1u)) >> 16;          // RNE
    ub = (ub + 0x7FFFu + ((ub >> 16) & 1u));
    return (ua & 0xFFFFu) | (ub & 0xFFFF0000u);
}

// 1D grid, XCD-affinity decode: slot = bid&7 -> (cg,b); mt = bid>>3.
// All blocks touching x-slab (b, channels 16cg..16cg+15) run on one XCD's L2.
__global__ __launch_bounds__(THREADS, 4) void conv_main(
    const float* __restrict__ x,
    const short* __restrict__ Wb,      // bf16 W, row-major [COUT][KK]
    const float* __restrict__ bias,
    const int*   __restrict__ idx,
    float*       __restrict__ out)
{
    __shared__ short tile[16 * STRIDE];                      // 57600 B -> 2 blk/CU

    const int bid  = blockIdx.x;
    const int slot = bid & 7;
    const int cg   = slot >> 1;
    const int b    = slot & 1;
    const int mt   = bid >> 3;
    const int t    = threadIdx.x;
    const int M0   = mt * LM;
    const int mEnd = min(M0 + MSTAGE, SEVEN_N);
    const float* xb = x + (size_t)b * Nv * CIN;

    // ---- gather: 4 threads per m-pair; ALL 14 loads forced in flight ----
    const int q    = t & 3;
    const int pidl = t >> 2;          // 0..127
    const int xoff = cg * 16 + q * 4;

    int iv0[PASSES], iv1[PASSES];
    #pragma unroll
    for (int p = 0; p < PASSES; ++p) {
        const int m0 = M0 + 2 * (p * PPP + pidl);
        const bool ok = (m0 < mEnd);
        iv0[p] = ok ? idx[m0] : 0;
        iv1[p] = (ok && m0 + 1 < mEnd) ? idx[m0 + 1] : 0;
    }
    float4 v0[PASSES], v1[PASSES];
    #pragma unroll
    for (int p = 0; p < PASSES; ++p) {   // 14 independent 16B loads per thread
        v0[p] = *(const float4*)(xb + (size_t)iv0[p] * CIN + xoff);
        v1[p] = *(const float4*)(xb + (size_t)iv1[p] * CIN + xoff);
    }
    // Forbid the compiler from sinking loads past this point (it otherwise
    // software-pipelines to depth ~2-3 to save VGPRs; r4 showed VGPR=52).
    __builtin_amdgcn_sched_barrier(0);
    #pragma unroll
    for (int p = 0; p < PASSES; ++p) {
        const int m0 = M0 + 2 * (p * PPP + pidl);
        if (m0 < mEnd) {
            const float a0[4] = {v0[p].x, v0[p].y, v0[p].z, v0[p].w};
            const float a1[4] = {v1[p].x, v1[p].y, v1[p].z, v1[p].w};
            #pragma unroll
            for (int i = 0; i < 4; ++i) {
                const int c     = q * 4 + i;
                const int shift = (6 * c) & 7;               // == Ta&7, even
                const int ppos  = (m0 - M0) + shift;
                *(unsigned*)&tile[c * STRIDE + ppos] = pack2_bf16(a0[i], a1[i]);
            }
        }
    }
    __syncthreads();

    // ---- compute: 12 tasks (oc = task&3, r = task>>2) over 8 waves ----
    const int lane = t & 63;
    const int w    = t >> 6;          // 0..7
    const int col  = lane & 15;
    const int hi   = lane >> 4;
    const int oc   = w & 3;           // same for task w and w+8 -> share bfrag

    const short* wbase = Wb + (oc * 16 + col) * KK + 8 * hi;
    bf8_t bfrag[14];
    #pragma unroll
    for (int k0 = 0; k0 < 14; ++k0)
        bfrag[k0] = *(const bf8_t*)(wbase + 32 * k0);

    const int Ca  = cg * 16 + col;
    const int Ta  = Ca * SEVEN_N + M0;
    const int d0a = (448 - (Ta % 448)) % 448;
    const int sha = Ta & 7;
    const short* abase0 = &tile[col * STRIDE + d0a + sha + 8 * hi];
    const float bo = bias[oc * 16 + col];

    for (int task = w; task < 12; task += 8) {
        const int r = task >> 2;                 // 0..2
        const short* abase = abase0 + 448 * r;

        f32x4 acc = (f32x4){0.f, 0.f, 0.f, 0.f};
        #pragma unroll
        for (int k0 = 0; k0 < 14; ++k0) {
            const bf8_t afrag = *(const bf8_t*)(abase + 32 * k0);
            acc = __builtin_amdgcn_mfma_f32_16x16x32_bf16(afrag, bfrag[k0], acc, 0, 0, 0);
        }

        // D[row=channel][col=o], channel = 4*hi + i
        #pragma unroll
        for (int i = 0; i < 4; ++i) {
            const int c_s = 4 * hi + i;
            const int Cs  = cg * 16 + c_s;
            const int Ts  = Cs * SEVEN_N + M0;
            const int d0s = (448 - (Ts % 448)) % 448;
            const int sr  = M0 + d0s + 448 * r;
            if (sr + 448 <= SEVEN_N) {           // skip channel-straddling rows
                const int n = (Ts + d0s) / 448 + r;
                out[((size_t)b * Nv + n) * COUT + oc * 16 + col] = acc[i] + bo;
            }
        }
    }
}

// Channel-straddling rows (<=63 per batch): exact fp32, j-parallel.
__global__ __launch_bounds__(256) void conv_cleanup(
    const float* __restrict__ x,
    const float* __restrict__ W,
    const float* __restrict__ bias,
    const int*   __restrict__ idx,
    float*       __restrict__ out)
{
    __shared__ float part[4][64];
    const int C = blockIdx.x;                    // 0..63
    const int b = blockIdx.y;
    const int t = threadIdx.x;
    const int o = t & 63;
    const int p = t >> 6;                        // j-quarter
    const int n = (int)(((long long)(C + 1) * SEVEN_N + 447) / 448) - 1;
    const int s = 448 * n - C * SEVEN_N;
    if (s + 448 <= SEVEN_N) return;              // no straddle at this boundary
    const float* xb = x + (size_t)b * Nv * CIN;
    float acc = 0.f;
    for (int j = p * 112; j < (p + 1) * 112; ++j) {
        int m = s + j, c = C;
        if (m >= SEVEN_N) { m -= SEVEN_N; c += 1; }
        acc += xb[(size_t)idx[m] * CIN + c] * W[o * KK + j];
    }
    part[p][o] = acc;
    __syncthreads();
    if (p == 0)
        out[((size_t)b * Nv + n) * COUT + o] =
            part[0][o] + part[1][o] + part[2][o] + part[3][o] + bias[o];
}

__global__ void wconv(const float* __restrict__ W, short* __restrict__ Wb) {
    const int i = blockIdx.x * 256 + threadIdx.x;
    if (i < COUT * KK) {
        unsigned u = __builtin_bit_cast(unsigned, W[i]);
        u = (u + 0x7FFFu + ((u >> 16) & 1u)) >> 16;
        Wb[i] = (short)u;
    }
}

extern "C" void kernel_launch(void* const* d_in, const int* in_sizes, int n_in,
                              void* d_out, int out_size, void* d_ws, size_t ws_size,
                              hipStream_t stream) {
    const float* x    = (const float*)d_in[0];
    const float* W    = (const float*)d_in[1];
    const float* bias = (const float*)d_in[2];
    const int*   idx  = (const int*)d_in[3];
    float*       out  = (float*)d_out;
    short*       Wb   = (short*)d_ws;           // 57344 B scratch

    hipLaunchKernelGGL(wconv, dim3((COUT * KK + 255) / 256), dim3(256), 0, stream, W, Wb);
    hipLaunchKernelGGL(conv_main, dim3(NT * 8), dim3(THREADS), 0, stream,
                       x, Wb, bias, idx, out);
    hipLaunchKernelGGL(conv_cleanup, dim3(CIN, Bc), dim3(256), 0, stream,
                       x, W, bias, idx, out);
}